// Round 1
// baseline (481.394 us; speedup 1.0000x reference)
//
#include <hip/hip_runtime.h>
#include <hip/hip_bf16.h>

// Problem constants (from reference)
#define BS 4
#define LEN 5440            // LEN_Q == LEN_V
#define ROWS (BS * LEN)     // 21760 (== 340 * 64)
#define EMBED 256
#define HEADS 8
#define CHAN 32             // C = EMBED/HEADS
#define LEVELS 4
#define POINTS 4

// ---------------------------------------------------------------------------
// Classic f32 tiled GEMM with bias:  C[M,N] = A[M,K] @ B[K,N] + bias[N]
// BM=BN=64, BK=16, 256 threads, each thread computes 4x4.
// Requires M%64==0, N%64==0, K%16==0 (true for all our shapes).
// ---------------------------------------------------------------------------
#define BM 64
#define BN 64
#define BK 16

__global__ __launch_bounds__(256) void gemm_bias_f32(
    const float* __restrict__ A, const float* __restrict__ B,
    const float* __restrict__ bias, float* __restrict__ C,
    int M, int N, int K)
{
    __shared__ float As[BK][BM];   // transposed: As[k][m]
    __shared__ float Bs[BK][BN];

    const int tid = threadIdx.x;
    const int tr = tid >> 4;        // 0..15 -> row group (4 rows each)
    const int tc = tid & 15;        // 0..15 -> col group (4 cols each)
    const int blockRow = blockIdx.y * BM;
    const int blockCol = blockIdx.x * BN;

    // A-tile load mapping: 64x16 tile, each thread loads float4 along K
    const int a_m = tid >> 2;           // 0..63
    const int a_k = (tid & 3) * 4;      // 0,4,8,12
    // B-tile load mapping: 16x64 tile, each thread loads float4 along N
    const int b_k = tid >> 4;           // 0..15
    const int b_n = (tid & 15) * 4;     // 0..60

    float acc[4][4] = {};

    for (int k0 = 0; k0 < K; k0 += BK) {
        float4 av = *(const float4*)(A + (size_t)(blockRow + a_m) * K + k0 + a_k);
        As[a_k + 0][a_m] = av.x;
        As[a_k + 1][a_m] = av.y;
        As[a_k + 2][a_m] = av.z;
        As[a_k + 3][a_m] = av.w;
        float4 bv = *(const float4*)(B + (size_t)(k0 + b_k) * N + blockCol + b_n);
        *(float4*)&Bs[b_k][b_n] = bv;
        __syncthreads();

#pragma unroll
        for (int kk = 0; kk < BK; ++kk) {
            float a0 = As[kk][tr * 4 + 0];
            float a1 = As[kk][tr * 4 + 1];
            float a2 = As[kk][tr * 4 + 2];
            float a3 = As[kk][tr * 4 + 3];
            float b0 = Bs[kk][tc * 4 + 0];
            float b1 = Bs[kk][tc * 4 + 1];
            float b2 = Bs[kk][tc * 4 + 2];
            float b3 = Bs[kk][tc * 4 + 3];
            acc[0][0] += a0 * b0; acc[0][1] += a0 * b1; acc[0][2] += a0 * b2; acc[0][3] += a0 * b3;
            acc[1][0] += a1 * b0; acc[1][1] += a1 * b1; acc[1][2] += a1 * b2; acc[1][3] += a1 * b3;
            acc[2][0] += a2 * b0; acc[2][1] += a2 * b1; acc[2][2] += a2 * b2; acc[2][3] += a2 * b3;
            acc[3][0] += a3 * b0; acc[3][1] += a3 * b1; acc[3][2] += a3 * b2; acc[3][3] += a3 * b3;
        }
        __syncthreads();
    }

    const int col = blockCol + tc * 4;
    float bx = bias[col + 0], by = bias[col + 1], bz = bias[col + 2], bw = bias[col + 3];
#pragma unroll
    for (int i = 0; i < 4; ++i) {
        int row = blockRow + tr * 4 + i;
        float4 o;
        o.x = acc[i][0] + bx;
        o.y = acc[i][1] + by;
        o.z = acc[i][2] + bz;
        o.w = acc[i][3] + bw;
        *(float4*)(C + (size_t)row * N + col) = o;
    }
}

// ---------------------------------------------------------------------------
// Fused softmax + multi-scale bilinear sampling.
// One block (256 threads) per (b, q). Thread t: head h = t>>5, channel c = t&31.
// Reads off_out[b,q,256], attn_out[b,q,128], ref_points[b,q,4,2], v[b,:,256].
// Writes pre[b,q,256] where channel index == h*32 + c == t.
// ---------------------------------------------------------------------------
__global__ __launch_bounds__(256) void msda_sample(
    const float* __restrict__ v,         // [BS][LEN][256]
    const float* __restrict__ ref_pts,   // [BS][LEN][4][2]
    const float* __restrict__ off_out,   // [BS][LEN][256]
    const float* __restrict__ attn_out,  // [BS][LEN][128]
    float* __restrict__ pre)             // [BS][LEN][256]
{
    const int bq = blockIdx.x;
    const int b = bq / LEN;
    const int t = threadIdx.x;
    const int h = t >> 5;

    __shared__ float s_off[256];
    __shared__ float s_aw[128];
    __shared__ float s_ref[8];

    s_off[t] = off_out[(size_t)bq * 256 + t];
    if (t < 128) s_aw[t] = attn_out[(size_t)bq * 128 + t];
    if (t < 8)   s_ref[t] = ref_pts[(size_t)bq * 8 + t];
    __syncthreads();

    // softmax over this head's 16 logits (computed redundantly per thread; cheap)
    float m = -1e30f;
#pragma unroll
    for (int i = 0; i < 16; ++i) m = fmaxf(m, s_aw[h * 16 + i]);
    float e[16];
    float denom = 0.f;
#pragma unroll
    for (int i = 0; i < 16; ++i) { e[i] = __expf(s_aw[h * 16 + i] - m); denom += e[i]; }
    const float inv = 1.f / denom;

    const float* vb = v + (size_t)b * LEN * 256;

    const int lsz[4]   = {64, 32, 16, 8};
    const int lstart[4] = {0, 4096, 5120, 5376};

    float acc = 0.f;
#pragma unroll
    for (int l = 0; l < 4; ++l) {
        const float rx = s_ref[l * 2 + 0];
        const float ry = s_ref[l * 2 + 1];
        const int iw = lsz[l], ih = lsz[l];
        const int st = lstart[l];
        const float fiw = (float)iw, fih = (float)ih;
#pragma unroll
        for (int p = 0; p < 4; ++p) {
            const int oidx = ((h * 4 + l) * 4 + p) * 2;
            // loc = ref + off / (w,h); then x = loc_x*w - 0.5, y = loc_y*h - 0.5
            const float x = (rx + s_off[oidx + 0] / fiw) * fiw - 0.5f;
            const float y = (ry + s_off[oidx + 1] / fih) * fih - 0.5f;
            const float x0f = floorf(x), y0f = floorf(y);
            const int x0 = (int)x0f, y0 = (int)y0f;
            const float fx = x - x0f, fy = y - y0f;
            const float w00 = (1.f - fx) * (1.f - fy);   // (y0, x0)
            const float w10 = (1.f - fx) * fy;           // (y1, x0)
            const float w01 = fx * (1.f - fy);           // (y0, x1)
            const float w11 = fx * fy;                   // (y1, x1)

            float s = 0.f;
            // tap (y0, x0)
            if (x0 >= 0 && x0 <= iw - 1 && y0 >= 0 && y0 <= ih - 1)
                s += vb[(size_t)(st + y0 * iw + x0) * 256 + t] * w00;
            // tap (y0+1, x0)
            if (x0 >= 0 && x0 <= iw - 1 && y0 + 1 >= 0 && y0 + 1 <= ih - 1)
                s += vb[(size_t)(st + (y0 + 1) * iw + x0) * 256 + t] * w10;
            // tap (y0, x0+1)
            if (x0 + 1 >= 0 && x0 + 1 <= iw - 1 && y0 >= 0 && y0 <= ih - 1)
                s += vb[(size_t)(st + y0 * iw + x0 + 1) * 256 + t] * w01;
            // tap (y0+1, x0+1)
            if (x0 + 1 >= 0 && x0 + 1 <= iw - 1 && y0 + 1 >= 0 && y0 + 1 <= ih - 1)
                s += vb[(size_t)(st + (y0 + 1) * iw + x0 + 1) * 256 + t] * w11;

            acc += s * (e[l * 4 + p] * inv);
        }
    }

    pre[(size_t)bq * 256 + t] = acc;
}

// ---------------------------------------------------------------------------
// Launch
// ---------------------------------------------------------------------------
extern "C" void kernel_launch(void* const* d_in, const int* in_sizes, int n_in,
                              void* d_out, int out_size, void* d_ws, size_t ws_size,
                              hipStream_t stream) {
    const float* query    = (const float*)d_in[0];   // [4][5440][256]
    const float* ref_pts  = (const float*)d_in[1];   // [4][5440][4][2]
    const float* value    = (const float*)d_in[2];   // [4][5440][256]
    // d_in[3] pad_mask: all ones in this problem -> no-op
    // d_in[4] train: unused
    const float* vproj_w  = (const float*)d_in[5];   // [256][256]
    const float* vproj_b  = (const float*)d_in[6];   // [256]
    const float* off_w    = (const float*)d_in[7];   // [256][256]
    const float* off_b    = (const float*)d_in[8];   // [256]
    const float* attn_w   = (const float*)d_in[9];   // [256][128]
    const float* attn_b   = (const float*)d_in[10];  // [128]
    const float* out_w    = (const float*)d_in[11];  // [256][256]
    const float* out_b    = (const float*)d_in[12];  // [256]
    float* out = (float*)d_out;                      // [4][5440][256]

    float* ws = (float*)d_ws;
    float* v_buf    = ws;                      // ROWS*256 = 5,570,560 floats
    float* off_buf  = v_buf + (size_t)ROWS * 256;
    float* attn_buf = off_buf + (size_t)ROWS * 256;  // ROWS*128
    float* pre_buf  = attn_buf + (size_t)ROWS * 128;

    dim3 blk(256);
    dim3 g256(EMBED / BN, ROWS / BM);   // N=256
    dim3 g128(128 / BN, ROWS / BM);     // N=128

    // 1. v = value @ vproj_w + vproj_b
    gemm_bias_f32<<<g256, blk, 0, stream>>>(value, vproj_w, vproj_b, v_buf, ROWS, 256, 256);
    // 2. off = query @ off_w + off_b
    gemm_bias_f32<<<g256, blk, 0, stream>>>(query, off_w, off_b, off_buf, ROWS, 256, 256);
    // 3. attn = query @ attn_w + attn_b
    gemm_bias_f32<<<g128, blk, 0, stream>>>(query, attn_w, attn_b, attn_buf, ROWS, 128, 256);
    // 4. softmax + bilinear sampling
    msda_sample<<<dim3(ROWS), blk, 0, stream>>>(v_buf, ref_pts, off_buf, attn_buf, pre_buf);
    // 5. out = pre @ out_w + out_b
    gemm_bias_f32<<<g256, blk, 0, stream>>>(pre_buf, out_w, out_b, out, ROWS, 256, 256);
}

// Round 2
// 218.802 us; speedup vs baseline: 2.2001x; 2.2001x over previous
//
#include <hip/hip_runtime.h>
#include <hip/hip_bf16.h>
#include <stdint.h>
#include <type_traits>

#define BS 4
#define LEN 5440
#define ROWS (BS * LEN)     // 21760 = 340 * 64
#define EMBED 256

typedef __bf16 bf16;
typedef __bf16 bf16x2 __attribute__((ext_vector_type(2)));
typedef __bf16 bf16x4 __attribute__((ext_vector_type(4)));
typedef __bf16 bf16x8 __attribute__((ext_vector_type(8)));
typedef float f32x4 __attribute__((ext_vector_type(4)));

// ---------------------------------------------------------------------------
// f32 -> bf16 cast, float4 granularity (n4 = n/4)
// ---------------------------------------------------------------------------
__global__ __launch_bounds__(256) void cast_to_bf16(const float* __restrict__ x,
                                                    bf16* __restrict__ y, int n4) {
    int i = blockIdx.x * 256 + threadIdx.x;
    if (i < n4) {
        float4 v = ((const float4*)x)[i];
        bf16x4 o = { (bf16)v.x, (bf16)v.y, (bf16)v.z, (bf16)v.w };
        ((bf16x4*)y)[i] = o;
    }
}

// ---------------------------------------------------------------------------
// Weight prep: W[K=256][N] f32 row-major  ->  BT[N][256] bf16 (transposed).
// grid = N blocks, 256 threads (one per k).
// ---------------------------------------------------------------------------
__global__ __launch_bounds__(256) void prep_bt(const float* __restrict__ W,
                                               bf16* __restrict__ BT, int N) {
    int n = blockIdx.x;
    int k = threadIdx.x;
    BT[(size_t)n * 256 + k] = (bf16)W[(size_t)k * N + n];
}

// ---------------------------------------------------------------------------
// bf16 MFMA GEMM:  C[M][N] = A[M][256] @ B[256][N] + bias
//   A  : bf16 row-major, K=256 fixed
//   BT : bf16 [N][256]  (transposed weight, k contiguous per row)
//   Block: 256 thr = 4 waves; block tile 64 rows x 128 cols.
//   Wave w: rows m0 + w*16 .. +15, all 128 cols (8 ntiles of 16).
//   Entire BT column-block (128 rows x 256 k = 64 KB) staged in LDS once;
//   16B chunks XOR-swizzled by (n&7) to spread banks.
// ---------------------------------------------------------------------------
template <typename OutT>
__global__ __launch_bounds__(256) void gemm_mfma(
    const bf16* __restrict__ A, const bf16* __restrict__ BT,
    const float* __restrict__ bias, OutT* __restrict__ C, int N)
{
    __shared__ bf16 sB[128 * 256];   // 65536 B, chunk-swizzled

    const int tid  = threadIdx.x;
    const int wave = tid >> 6;
    const int lane = tid & 63;
    const int l15  = lane & 15;
    const int quad = lane >> 4;
    const int sw   = l15 & 7;

    const int n0 = blockIdx.x * 128;
    const int m0 = blockIdx.y * 64;

    // stage BT[n0 .. n0+127][0..255] -> sB with chunk swizzle
    {
        const int4* src = (const int4*)(BT + (size_t)n0 * 256);  // 16B = 8 bf16
        int4* dst = (int4*)sB;
        // 128 rows * 32 chunks = 4096 chunks; 16 per thread
#pragma unroll
        for (int it = 0; it < 16; ++it) {
            int c = tid + it * 256;
            int n = c >> 5;
            int kc = c & 31;
            dst[(n << 5) | (kc ^ (n & 7))] = src[c];
        }
    }
    __syncthreads();

    const int row = m0 + wave * 16 + l15;
    const bf16* arow = A + (size_t)row * 256 + quad * 8;

    f32x4 acc[8] = {};

#pragma unroll
    for (int ki = 0; ki < 8; ++ki) {
        bf16x8 a = *(const bf16x8*)(arow + ki * 32);
        const int kc = (ki << 2) + quad;   // chunk index within row, 0..31
#pragma unroll
        for (int ni = 0; ni < 8; ++ni) {
            const int nn = (ni << 4) + l15;
            bf16x8 b = *(const bf16x8*)(sB + (((nn << 5) | (kc ^ sw)) << 3));
            acc[ni] = __builtin_amdgcn_mfma_f32_16x16x32_bf16(a, b, acc[ni], 0, 0, 0);
        }
    }

    // epilogue: lane holds D[row = quad*4 + r][col = l15] per ntile
#pragma unroll
    for (int ni = 0; ni < 8; ++ni) {
        const int col = n0 + (ni << 4) + l15;
        const float bv = bias[col];
#pragma unroll
        for (int r = 0; r < 4; ++r) {
            const int rr = m0 + wave * 16 + (quad << 2) + r;
            float val = acc[ni][r] + bv;
            if constexpr (std::is_same_v<OutT, float>)
                C[(size_t)rr * N + col] = val;
            else
                C[(size_t)rr * N + col] = (bf16)val;
        }
    }
}

// ---------------------------------------------------------------------------
// Fused softmax + multi-scale bilinear sampling (bf16 in/out).
// Block = 256 thr = 4 queries x 64 lanes. Lane u: head h = u>>3, channels
// (u&7)*4 .. +3 via bf16x4 gathers. Block->batch mapping keeps one batch's
// v (2.8 MB bf16) resident per XCD-pair L2.
// ---------------------------------------------------------------------------
__global__ __launch_bounds__(256) void msda_sample(
    const bf16* __restrict__ v,        // [BS][LEN][256]
    const float* __restrict__ ref_pts, // [BS][LEN][4][2]
    const bf16* __restrict__ off,      // [BS][LEN][256]
    const bf16* __restrict__ aw,       // [BS][LEN][128]
    bf16* __restrict__ pre)            // [BS][LEN][256]
{
    const int ib = blockIdx.x;
    const int b  = (ib & 7) >> 1;
    const int qg = ((ib >> 3) << 1) + (ib & 1);   // [0, 1360)
    const int q0 = qg * 4;
    const int tid = threadIdx.x;
    const int qi = tid >> 6;
    const int u  = tid & 63;
    const int h  = u >> 3;
    const int c8 = u & 7;

    __shared__ float s_off[4 * 256];
    __shared__ float s_aw[4 * 128];
    __shared__ float s_ref[4 * 8];

    const size_t rowbase = (size_t)(b * LEN + q0);
    {
        bf16x4 o = ((const bf16x4*)(off + rowbase * 256))[tid];
        s_off[tid * 4 + 0] = (float)o[0];
        s_off[tid * 4 + 1] = (float)o[1];
        s_off[tid * 4 + 2] = (float)o[2];
        s_off[tid * 4 + 3] = (float)o[3];
    }
    {
        bf16x2 a2 = ((const bf16x2*)(aw + rowbase * 128))[tid];
        s_aw[tid * 2 + 0] = (float)a2[0];
        s_aw[tid * 2 + 1] = (float)a2[1];
    }
    if (tid < 32) s_ref[tid] = ref_pts[rowbase * 8 + tid];
    __syncthreads();

    const float* so = s_off + qi * 256;
    const float* sa = s_aw + qi * 128;
    const float* sr = s_ref + qi * 8;

    // softmax over this head's 16 logits (redundant across the 8 lanes; cheap)
    float m = -1e30f;
#pragma unroll
    for (int i = 0; i < 16; ++i) m = fmaxf(m, sa[h * 16 + i]);
    float e[16];
    float denom = 0.f;
#pragma unroll
    for (int i = 0; i < 16; ++i) { e[i] = __expf(sa[h * 16 + i] - m); denom += e[i]; }
    const float inv = 1.f / denom;

    const bf16* vb = v + (size_t)b * LEN * 256 + h * 32 + c8 * 4;

    const int lsz[4]    = {64, 32, 16, 8};
    const int lstart[4] = {0, 4096, 5120, 5376};

    float a0 = 0.f, a1 = 0.f, a2 = 0.f, a3 = 0.f;
#pragma unroll
    for (int l = 0; l < 4; ++l) {
        const int iw = lsz[l];
        const int st = lstart[l];
        const float fiw = (float)iw;
        const float xbase = sr[l * 2 + 0] * fiw - 0.5f;
        const float ybase = sr[l * 2 + 1] * fiw - 0.5f;
#pragma unroll
        for (int p = 0; p < 4; ++p) {
            const int oidx = (h * 16 + l * 4 + p) * 2;
            const float x = xbase + so[oidx + 0];
            const float y = ybase + so[oidx + 1];
            const float x0f = floorf(x), y0f = floorf(y);
            const int x0 = (int)x0f, y0 = (int)y0f;
            const float fx = x - x0f, fy = y - y0f;
            const float wa = e[l * 4 + p] * inv;
            float w00 = (1.f - fx) * (1.f - fy) * wa;
            float w10 = (1.f - fx) * fy * wa;
            float w01 = fx * (1.f - fy) * wa;
            float w11 = fx * fy * wa;

            const bool xin0 = (x0 >= 0) & (x0 <= iw - 1);
            const bool xin1 = (x0 + 1 >= 0) & (x0 + 1 <= iw - 1);
            const bool yin0 = (y0 >= 0) & (y0 <= iw - 1);
            const bool yin1 = (y0 + 1 >= 0) & (y0 + 1 <= iw - 1);

            if (xin0 & yin0) {
                bf16x4 vv = *(const bf16x4*)(vb + (size_t)(st + y0 * iw + x0) * 256);
                a0 += (float)vv[0] * w00; a1 += (float)vv[1] * w00;
                a2 += (float)vv[2] * w00; a3 += (float)vv[3] * w00;
            }
            if (xin0 & yin1) {
                bf16x4 vv = *(const bf16x4*)(vb + (size_t)(st + (y0 + 1) * iw + x0) * 256);
                a0 += (float)vv[0] * w10; a1 += (float)vv[1] * w10;
                a2 += (float)vv[2] * w10; a3 += (float)vv[3] * w10;
            }
            if (xin1 & yin0) {
                bf16x4 vv = *(const bf16x4*)(vb + (size_t)(st + y0 * iw + x0 + 1) * 256);
                a0 += (float)vv[0] * w01; a1 += (float)vv[1] * w01;
                a2 += (float)vv[2] * w01; a3 += (float)vv[3] * w01;
            }
            if (xin1 & yin1) {
                bf16x4 vv = *(const bf16x4*)(vb + (size_t)(st + (y0 + 1) * iw + x0 + 1) * 256);
                a0 += (float)vv[0] * w11; a1 += (float)vv[1] * w11;
                a2 += (float)vv[2] * w11; a3 += (float)vv[3] * w11;
            }
        }
    }

    bf16x4 o = { (bf16)a0, (bf16)a1, (bf16)a2, (bf16)a3 };
    *(bf16x4*)(pre + (rowbase + qi) * 256 + h * 32 + c8 * 4) = o;
}

// ---------------------------------------------------------------------------
// Launch
// ---------------------------------------------------------------------------
extern "C" void kernel_launch(void* const* d_in, const int* in_sizes, int n_in,
                              void* d_out, int out_size, void* d_ws, size_t ws_size,
                              hipStream_t stream) {
    const float* query   = (const float*)d_in[0];
    const float* ref_pts = (const float*)d_in[1];
    const float* value   = (const float*)d_in[2];
    const float* vproj_w = (const float*)d_in[5];
    const float* vproj_b = (const float*)d_in[6];
    const float* off_w   = (const float*)d_in[7];
    const float* off_b   = (const float*)d_in[8];
    const float* attn_w  = (const float*)d_in[9];
    const float* attn_b  = (const float*)d_in[10];
    const float* out_w   = (const float*)d_in[11];
    const float* out_b   = (const float*)d_in[12];
    float* out = (float*)d_out;

    bf16* ws = (bf16*)d_ws;
    bf16* value_bf = ws;                                  // ROWS*256
    bf16* query_bf = value_bf + (size_t)ROWS * 256;       // ROWS*256
    bf16* v_bf     = query_bf + (size_t)ROWS * 256;       // ROWS*256
    bf16* off_bf   = v_bf     + (size_t)ROWS * 256;       // ROWS*256
    bf16* attn_bf  = off_bf   + (size_t)ROWS * 256;       // ROWS*128
    bf16* pre_bf   = attn_bf  + (size_t)ROWS * 128;       // ROWS*256
    bf16* bt_v     = pre_bf   + (size_t)ROWS * 256;       // 256*256
    bf16* bt_off   = bt_v     + 256 * 256;                // 256*256
    bf16* bt_attn  = bt_off   + 256 * 256;                // 128*256
    bf16* bt_out   = bt_attn  + 128 * 256;                // 256*256

    const int n4 = ROWS * 256 / 4;   // 1,392,640
    dim3 blk(256);

    cast_to_bf16<<<dim3((n4 + 255) / 256), blk, 0, stream>>>(value, value_bf, n4);
    cast_to_bf16<<<dim3((n4 + 255) / 256), blk, 0, stream>>>(query, query_bf, n4);

    prep_bt<<<dim3(256), blk, 0, stream>>>(vproj_w, bt_v, 256);
    prep_bt<<<dim3(256), blk, 0, stream>>>(off_w, bt_off, 256);
    prep_bt<<<dim3(128), blk, 0, stream>>>(attn_w, bt_attn, 128);
    prep_bt<<<dim3(256), blk, 0, stream>>>(out_w, bt_out, 256);

    gemm_mfma<bf16><<<dim3(2, 340), blk, 0, stream>>>(value_bf, bt_v, vproj_b, v_bf, 256);
    gemm_mfma<bf16><<<dim3(2, 340), blk, 0, stream>>>(query_bf, bt_off, off_b, off_bf, 256);
    gemm_mfma<bf16><<<dim3(1, 340), blk, 0, stream>>>(query_bf, bt_attn, attn_b, attn_bf, 128);

    msda_sample<<<dim3(5440), blk, 0, stream>>>(v_bf, ref_pts, off_bf, attn_bf, pre_bf);

    gemm_mfma<float><<<dim3(2, 340), blk, 0, stream>>>(pre_bf, bt_out, out_b, out, 256);
}

// Round 3
// 191.333 us; speedup vs baseline: 2.5160x; 1.1436x over previous
//
#include <hip/hip_runtime.h>
#include <hip/hip_bf16.h>
#include <stdint.h>
#include <type_traits>

#define BS 4
#define LEN 5440
#define ROWS (BS * LEN)     // 21760 = 340 * 64

typedef __bf16 bf16;
typedef __bf16 bf16x2 __attribute__((ext_vector_type(2)));
typedef __bf16 bf16x4 __attribute__((ext_vector_type(4)));
typedef __bf16 bf16x8 __attribute__((ext_vector_type(8)));
typedef float f32x4 __attribute__((ext_vector_type(4)));

// ---------------------------------------------------------------------------
// Weight prep (single dispatch): transpose+cast all 4 weight matrices into
// bf16 BT[N][256] layouts, and build the concatenated [off|attn] bias.
// grid = 897 blocks x 256 threads.
//   n in [0,256)   : bt_v    row n      <- vproj_w col n
//   n in [256,512) : bt_oa   row n-256  <- off_w   col n-256
//   n in [512,640) : bt_oa   row n-256  <- attn_w  col n-512
//   n in [640,896) : bt_out  row n-640  <- out_w   col n-640
//   n == 896       : bias_oa = [off_b | attn_b]
// ---------------------------------------------------------------------------
__global__ __launch_bounds__(256) void prep_weights(
    const float* __restrict__ vproj_w, const float* __restrict__ off_w,
    const float* __restrict__ attn_w, const float* __restrict__ out_w,
    const float* __restrict__ off_b, const float* __restrict__ attn_b,
    bf16* __restrict__ bt_v, bf16* __restrict__ bt_oa, bf16* __restrict__ bt_out,
    float* __restrict__ bias_oa)
{
    const int n = blockIdx.x;
    const int k = threadIdx.x;
    if (n == 896) {
        bias_oa[k] = off_b[k];
        if (k < 128) bias_oa[256 + k] = attn_b[k];
        return;
    }
    const float* W; bf16* dst; int col, N;
    if (n < 256)      { W = vproj_w; N = 256; col = n;       dst = bt_v   + n * 256; }
    else if (n < 512) { W = off_w;   N = 256; col = n - 256; dst = bt_oa  + (n - 256) * 256; }
    else if (n < 640) { W = attn_w;  N = 128; col = n - 512; dst = bt_oa  + (n - 256) * 256; }
    else              { W = out_w;   N = 256; col = n - 640; dst = bt_out + (n - 640) * 256; }
    dst[k] = (bf16)W[k * N + col];
}

// ---------------------------------------------------------------------------
// bf16 MFMA GEMM:  C[M][N] = A[M][256] @ B[256][N] + bias
//   A  : f32 or bf16 row-major (f32 is converted in-register)
//   BT : bf16 [N][256]  (transposed weight, k contiguous per row)
//   Block: 256 thr = 4 waves; tile 64 rows x 128 cols; whole K=256 staged
//   once in 64 KB LDS with 16B-chunk XOR swizzle; single barrier.
// ---------------------------------------------------------------------------
template <typename AT, typename OutT>
__global__ __launch_bounds__(256) void gemm_mfma(
    const AT* __restrict__ A, const bf16* __restrict__ BT,
    const float* __restrict__ bias, OutT* __restrict__ C, int N)
{
    __shared__ bf16 sB[128 * 256];   // 64 KB

    const int tid  = threadIdx.x;
    const int wave = tid >> 6;
    const int lane = tid & 63;
    const int l15  = lane & 15;
    const int quad = lane >> 4;
    const int sw   = l15 & 7;

    const int n0 = blockIdx.x * 128;
    const int m0 = blockIdx.y * 64;

    {
        const int4* src = (const int4*)(BT + (size_t)n0 * 256);
        int4* dst = (int4*)sB;
#pragma unroll
        for (int it = 0; it < 16; ++it) {
            int c = tid + it * 256;
            int n = c >> 5;
            int kc = c & 31;
            dst[(n << 5) | (kc ^ (n & 7))] = src[c];
        }
    }
    __syncthreads();

    const int row = m0 + wave * 16 + l15;
    const AT* arow = A + (size_t)row * 256 + quad * 8;

    f32x4 acc[8] = {};

#pragma unroll
    for (int ki = 0; ki < 8; ++ki) {
        bf16x8 a;
        if constexpr (std::is_same_v<AT, float>) {
            float4 f0 = *(const float4*)(arow + ki * 32);
            float4 f1 = *(const float4*)(arow + ki * 32 + 4);
            a = bf16x8{(bf16)f0.x, (bf16)f0.y, (bf16)f0.z, (bf16)f0.w,
                       (bf16)f1.x, (bf16)f1.y, (bf16)f1.z, (bf16)f1.w};
        } else {
            a = *(const bf16x8*)(arow + ki * 32);
        }
        const int kc = (ki << 2) + quad;
#pragma unroll
        for (int ni = 0; ni < 8; ++ni) {
            const int nn = (ni << 4) + l15;
            bf16x8 b = *(const bf16x8*)(sB + (((nn << 5) | (kc ^ sw)) << 3));
            acc[ni] = __builtin_amdgcn_mfma_f32_16x16x32_bf16(a, b, acc[ni], 0, 0, 0);
        }
    }

#pragma unroll
    for (int ni = 0; ni < 8; ++ni) {
        const int col = n0 + (ni << 4) + l15;
        const float bv = bias[col];
#pragma unroll
        for (int r = 0; r < 4; ++r) {
            const int rr = m0 + wave * 16 + (quad << 2) + r;
            float val = acc[ni][r] + bv;
            if constexpr (std::is_same_v<OutT, float>)
                C[(uint32_t)(rr * N + col)] = val;
            else
                C[(uint32_t)(rr * N + col)] = (bf16)val;
        }
    }
}

// ---------------------------------------------------------------------------
// Fused softmax + multi-scale bilinear sampling, two-phase.
// Block = 256 thr = 4 queries. Phase 1: per (q,h,point) compute 4 premultiplied
// tap weights (OOB->0) + 4 clamped 32-bit byte offsets into LDS. Phase 2:
// branch-free gather-accumulate, lane u: head u>>3, channels (u&7)*4..+3.
// ---------------------------------------------------------------------------
__global__ __launch_bounds__(256) void msda_sample(
    const bf16* __restrict__ v,        // [BS][LEN][256]
    const float* __restrict__ ref_pts, // [BS][LEN][4][2]
    const bf16* __restrict__ oa,       // [BS][LEN][384]: off 0..255, attn 256..383
    bf16* __restrict__ pre)            // [BS][LEN][256]
{
    const int ib = blockIdx.x;
    const int b  = (ib & 7) >> 1;                 // batch per XCD-pair
    const int qg = ((ib >> 3) << 1) + (ib & 1);   // [0,1360)
    const int q0 = qg * 4;
    const int tid = threadIdx.x;

    __shared__ float  s_ref[32];    // [4 q][8]
    __shared__ float  s_wn[512];    // [4 q][128] normalized softmax
    __shared__ float4 s_tw[512];    // [4 q][8 h][16 pt] premult tap weights
    __shared__ int4   s_to[512];    // matching byte offsets (incl. h*64)

    const uint32_t rowbase = (uint32_t)(b * LEN + q0);

    if (tid < 32) {
        s_ref[tid] = ref_pts[rowbase * 8 + tid];
        const int qi = tid >> 3, h = tid & 7;
        const bf16* ap = oa + (rowbase + qi) * 384 + 256 + h * 16;
        bf16x8 l0 = *(const bf16x8*)ap;
        bf16x8 l1 = *(const bf16x8*)(ap + 8);
        float lg[16];
#pragma unroll
        for (int i = 0; i < 8; ++i) { lg[i] = (float)l0[i]; lg[8 + i] = (float)l1[i]; }
        float m = -1e30f;
#pragma unroll
        for (int i = 0; i < 16; ++i) m = fmaxf(m, lg[i]);
        float s = 0.f;
#pragma unroll
        for (int i = 0; i < 16; ++i) { lg[i] = __expf(lg[i] - m); s += lg[i]; }
        const float inv = 1.f / s;
#pragma unroll
        for (int i = 0; i < 16; ++i) s_wn[qi * 128 + h * 16 + i] = lg[i] * inv;
    }
    __syncthreads();

    // Phase 1: 512 items, 2 per thread
#pragma unroll
    for (int it = 0; it < 2; ++it) {
        const int item = tid + it * 256;
        const int qi = item >> 7;
        const int h  = (item >> 4) & 7;
        const int pt = item & 15;
        const int l  = pt >> 2;
        const int iw = 64 >> l;
        const int st = (l == 0) ? 0 : ((l == 1) ? 4096 : ((l == 2) ? 5120 : 5376));
        const float fiw = (float)iw;

        bf16x2 ob = *(const bf16x2*)(oa + (rowbase + qi) * 384 + (h * 16 + pt) * 2);
        const float x = s_ref[qi * 8 + l * 2 + 0] * fiw - 0.5f + (float)ob[0];
        const float y = s_ref[qi * 8 + l * 2 + 1] * fiw - 0.5f + (float)ob[1];
        const float x0f = floorf(x), y0f = floorf(y);
        const int x0 = (int)x0f, y0 = (int)y0f;
        const int x1 = x0 + 1, y1 = y0 + 1;
        const float fx = x - x0f, fy = y - y0f;
        const float wa = s_wn[qi * 128 + h * 16 + pt];
        const float w00 = (1.f - fx) * (1.f - fy) * wa;
        const float w10 = (1.f - fx) * fy * wa;
        const float w01 = fx * (1.f - fy) * wa;
        const float w11 = fx * fy * wa;
        const bool xi0 = (x0 >= 0) & (x0 < iw);
        const bool xi1 = (x1 >= 0) & (x1 < iw);
        const bool yi0 = (y0 >= 0) & (y0 < iw);
        const bool yi1 = (y1 >= 0) & (y1 < iw);
        const int xc0 = min(max(x0, 0), iw - 1), xc1 = min(max(x1, 0), iw - 1);
        const int yc0 = min(max(y0, 0), iw - 1), yc1 = min(max(y1, 0), iw - 1);
        const int hb = h * 64;
        s_tw[item] = make_float4((xi0 & yi0) ? w00 : 0.f, (xi0 & yi1) ? w10 : 0.f,
                                 (xi1 & yi0) ? w01 : 0.f, (xi1 & yi1) ? w11 : 0.f);
        s_to[item] = make_int4(((st + yc0 * iw + xc0) << 9) + hb,
                               ((st + yc1 * iw + xc0) << 9) + hb,
                               ((st + yc0 * iw + xc1) << 9) + hb,
                               ((st + yc1 * iw + xc1) << 9) + hb);
    }
    __syncthreads();

    // Phase 2: branch-free gather-accumulate
    const int qi = tid >> 6;
    const int u  = tid & 63;
    const int h  = u >> 3;
    const int c8 = u & 7;
    const char* vbc = (const char*)(v + (uint32_t)b * (LEN * 256));
    const uint32_t lb = (uint32_t)(c8 * 8);
    const int base = (qi * 8 + h) * 16;

    float a0 = 0.f, a1 = 0.f, a2 = 0.f, a3 = 0.f;
#pragma unroll
    for (int pt = 0; pt < 16; ++pt) {
        const float4 w4 = s_tw[base + pt];
        const int4   o4 = s_to[base + pt];
#define TAP(OFF, W) { \
        uint2 d = *(const uint2*)(vbc + ((uint32_t)(OFF) + lb)); \
        a0 = fmaf(__uint_as_float(d.x << 16),          (W), a0); \
        a1 = fmaf(__uint_as_float(d.x & 0xffff0000u),  (W), a1); \
        a2 = fmaf(__uint_as_float(d.y << 16),          (W), a2); \
        a3 = fmaf(__uint_as_float(d.y & 0xffff0000u),  (W), a3); }
        TAP(o4.x, w4.x)
        TAP(o4.y, w4.y)
        TAP(o4.z, w4.z)
        TAP(o4.w, w4.w)
#undef TAP
    }

    bf16x4 o = {(bf16)a0, (bf16)a1, (bf16)a2, (bf16)a3};
    *(bf16x4*)(pre + (rowbase + qi) * 256 + h * 32 + c8 * 4) = o;
}

// ---------------------------------------------------------------------------
// Launch: 5 dispatches
// ---------------------------------------------------------------------------
extern "C" void kernel_launch(void* const* d_in, const int* in_sizes, int n_in,
                              void* d_out, int out_size, void* d_ws, size_t ws_size,
                              hipStream_t stream) {
    const float* query   = (const float*)d_in[0];
    const float* ref_pts = (const float*)d_in[1];
    const float* value   = (const float*)d_in[2];
    const float* vproj_w = (const float*)d_in[5];
    const float* vproj_b = (const float*)d_in[6];
    const float* off_w   = (const float*)d_in[7];
    const float* off_b   = (const float*)d_in[8];
    const float* attn_w  = (const float*)d_in[9];
    const float* attn_b  = (const float*)d_in[10];
    const float* out_w   = (const float*)d_in[11];
    const float* out_b   = (const float*)d_in[12];
    float* out = (float*)d_out;

    bf16* ws = (bf16*)d_ws;
    bf16* v_bf    = ws;                                // ROWS*256
    bf16* oa_bf   = v_bf   + (size_t)ROWS * 256;       // ROWS*384
    bf16* pre_bf  = oa_bf  + (size_t)ROWS * 384;       // ROWS*256
    bf16* bt_v    = pre_bf + (size_t)ROWS * 256;       // 256*256
    bf16* bt_oa   = bt_v   + 256 * 256;                // 384*256
    bf16* bt_out  = bt_oa  + 384 * 256;                // 256*256
    float* bias_oa = (float*)(bt_out + 256 * 256);     // 384 f32

    dim3 blk(256);

    prep_weights<<<dim3(897), blk, 0, stream>>>(vproj_w, off_w, attn_w, out_w,
                                                off_b, attn_b, bt_v, bt_oa, bt_out, bias_oa);

    gemm_mfma<float, bf16><<<dim3(2, 340), blk, 0, stream>>>(value, bt_v, vproj_b, v_bf, 256);
    gemm_mfma<float, bf16><<<dim3(3, 340), blk, 0, stream>>>(query, bt_oa, bias_oa, oa_bf, 384);

    msda_sample<<<dim3(5440), blk, 0, stream>>>(v_bf, ref_pts, oa_bf, pre_bf);

    gemm_mfma<bf16, float><<<dim3(2, 340), blk, 0, stream>>>(pre_bf, bt_out, out_b, out, 256);
}